// Round 5
// baseline (431.754 us; speedup 1.0000x reference)
//
#include <hip/hip_runtime.h>

#define K_TAGS 50
#define T_MAX 256
#define START_TAG 48
#define END_TAG 49
#define LOG2E 1.4426950408889634f
#define LN2 0.6931471805599453f
#define KK 2500    // dwords per 50x50 step matrix
#define LDSN 3072  // staged floats per LDS buffer (256 thr x 12)

// hardware transcendentals: v_exp_f32 is 2^x, v_log_f32 is log2(x)
#define EXP2F(x) __builtin_amdgcn_exp2f(x)
#define LOG2F(x) __builtin_amdgcn_logf(x)

__device__ __forceinline__ float rdlane(float v, int i) {
    return __int_as_float(__builtin_amdgcn_readlane(__float_as_int(v), i));
}

// Raw barrier with LDS-only drain (0xC07F = vmcnt(63) expcnt(7) lgkmcnt(0)):
// ds_write visibility without draining the global-load pipeline. Builtin, not
// inline asm (rounds 2/3: asm "memory" clobber => conservative full drain).
__device__ __forceinline__ void barrier_lds() {
    __builtin_amdgcn_sched_barrier(0);
    __builtin_amdgcn_s_waitcnt(0xC07F);
    __builtin_amdgcn_s_barrier();
    __builtin_amdgcn_sched_barrier(0);
}

// BLOCK-COOPERATIVE STAGING + LEAN RECURRENCE, one direction per block.
//   grid = 2*B blocks x 256 thr: block (2b+0) = FORWARD half of batch b,
//   block (2b+1) = BACKWARD half, meeting at m=(len-2)/2. 256 blocks ~ 1/CU.
// Round-4 lesson: per-wave exp/load issue (13 each) sat on every barrier-arrival
// path. Now staging is LINEAR and block-wide: per step each thread does
// 3x global dwordx4 (G(s+3), 2 steps in flight), 12 exps + 3x ds_write_b128
// (G'(s+1) -> LDS double buffer). The recurrence reads its 13 operands straight
// from LDS (fwd: G'[rb+r][jc]; bwd: G'[jc][rb+r]), 13 FMA w/ readlane(L),
// 4-partial LDS reduce + shared-exponent rescale. ONE barrier per step.
// Scaled-linear numerics identical to rounds 0-4: true log2-val = M + log2(L).
__global__ __launch_bounds__(256, 1) void crf_fwd_kernel(
    const float* __restrict__ scores, const int* __restrict__ targets,
    const int* __restrict__ lengths, float* __restrict__ accum,
    float* __restrict__ uv)
{
    const int b    = blockIdx.x >> 1;
    const int dir  = blockIdx.x & 1;      // 0 = forward, 1 = backward
    const int tid  = threadIdx.x;
    const int wave = tid >> 6;
    const int lane = tid & 63;
    const int len  = lengths[b];
    const float* __restrict__ sp = scores + (size_t)b * T_MAX * KK;
    const int jc  = (lane < K_TAGS) ? lane : (K_TAGS - 1);
    const int rb  = 13 * wave;            // reduction chunk [rb, rb+13)
    const int lin = tid * 12;             // linear float index for staging

    __shared__ float Gds[2][LDSN];        // double-buffered exp'd G (24 KB)
    __shared__ float pbuf[2][256];        // double-buffered per-wave partials

    const int m = (len - 2) / 2;          // fwd applies G_s, s=1..m
    int count = dir ? (len - 2 - m) : m;  // recurrence steps this block runs
    if (count < 0) count = 0;

    // ---- gold score: fwd block only, one timestep per thread ----
    if (dir == 0) {
        float g = 0.f;
        if (tid < len) g = sp[(size_t)tid * KK + targets[b * T_MAX + tid]];
        #pragma unroll
        for (int off = 32; off; off >>= 1) g += __shfl_down(g, off, 64);
        if (lane == 0) atomicAdd(&accum[1], g);
    }

    // ---- init L/M, replicated in every wave ----
    float L, M;
    if (dir == 0) {
        float bc = sp[START_TAG * K_TAGS + jc] * LOG2E;   // alpha0 row
        M = rdlane(bc, 0);
        L = EXP2F(bc - M);
    } else {
        M = 0.f;
        if (len >= 2)   // fold t=len-1: v = exp(s[:,END])
            L = EXP2F(sp[(size_t)(len - 1) * KK + jc * K_TAGS + END_TAG] * LOG2E);
        else
            L = (jc == END_TAG) ? 1.f : 0.f;
    }

    if (count > 0) {
        float4 R4[3][3];                  // 3-set load pipeline (2 steps in flight)

        auto issue_loads = [&](float4 (&dst)[3], int q) {
            int ss = (q <= count) ? q : count;            // clamp; surplus unused
            int tt = dir ? (len - 1 - ss) : ss;           // matrix time (<= 254)
            const float4* gp = (const float4*)(sp + (size_t)tt * KK + lin);
            dst[0] = gp[0]; dst[1] = gp[1]; dst[2] = gp[2];
        };
        auto exp_write = [&](float* gb, const float4 (&src)[3]) {
            float4* gw = (float4*)(gb + lin);
            #pragma unroll
            for (int k = 0; k < 3; ++k) {
                float4 v = src[k], w;
                w.x = EXP2F(v.x * LOG2E); w.y = EXP2F(v.y * LOG2E);
                w.z = EXP2F(v.z * LOG2E); w.w = EXP2F(v.w * LOG2E);
                gw[k] = w;
            }
        };

        // prologue: loads for steps 1,2,3 -> sets 1,2,0; exp step 1 -> Gds[1]
        issue_loads(R4[1], 1);
        issue_loads(R4[2], 2);
        issue_loads(R4[0], 3);
        __builtin_amdgcn_sched_barrier(0);
        exp_write(Gds[1], R4[1]);
        barrier_lds();

        int s = 1;
        while (s <= count) {
            #pragma unroll
            for (int u = 0; u < 6; ++u) {
                const int PLd = (1 + u) % 3;   // set receiving loads_for(s+3)
                const int PEx = (2 + u) % 3;   // set holding loads_for(s+1)
                const int PWr = u & 1;         // Gds parity for G'(s+1)
                const int PRd = (1 + u) & 1;   // Gds parity for G'(s); pbuf parity
                const bool live = (s <= count);

                if (live) {
                    // A) prefetch G(s+3): 3x dwordx4, stays in flight 2 steps
                    issue_loads(R4[PLd], s + 3);
                    // B) exp G(s+1) (loaded 2 steps ago) -> LDS double buffer
                    exp_write(Gds[PWr], R4[PEx]);
                    // C) recurrence step s: 13 LDS operands x readlane(L) -> partial
                    {
                        const float* g = Gds[PRd];
                        float a0 = 0.f, a1 = 0.f, a2 = 0.f;
                        #pragma unroll
                        for (int r = 0; r < 13; ++r) {
                            int idx = dir ? (jc * K_TAGS + rb + r)
                                          : ((rb + r) * K_TAGS + jc);
                            float gv = g[idx];
                            if (r >= 11 && rb + r >= K_TAGS) gv = 0.f; // wave-3 tail
                            float lv = rdlane(L, rb + r);
                            if ((r % 3) == 0)      a0 = __builtin_fmaf(gv, lv, a0);
                            else if ((r % 3) == 1) a1 = __builtin_fmaf(gv, lv, a1);
                            else                   a2 = __builtin_fmaf(gv, lv, a2);
                        }
                        pbuf[PRd][(wave << 6) + lane] = (a0 + a1) + a2;
                    }
                }
                // D) one barrier per step (lgkm only; vmcnt stays counted)
                barrier_lds();
                // E) combine partials + shared-exponent rescale (replicated)
                if (live) {
                    float p0 = pbuf[PRd][jc];
                    float p1 = pbuf[PRd][64 + jc];
                    float p2 = pbuf[PRd][128 + jc];
                    float p3 = pbuf[PRd][192 + jc];
                    float sum = (p0 + p1) + (p2 + p3);
                    int   ei = (__float_as_int(rdlane(sum, 0)) >> 23) & 0xFF;
                    float scale = __int_as_float((254 - ei) << 23);   // 2^-(ei-127)
                    L = sum * scale;
                    M += (float)(ei - 127);
                }
                ++s;
            }
        }
    }

    // ---- publish result vector for the combine kernel ----
    if (wave == 0) {
        float* w = uv + (size_t)(dir ? (gridDim.x >> 1) + b : b) * 64;
        if (lane < K_TAGS) w[lane] = L;
        if (lane == 0)     w[K_TAGS] = M;
    }
}

// per-batch combine: Z_b = Mu + Mv + log2(sum_j u[j]*v[j])
__global__ void combine_kernel(const float* __restrict__ uv,
                               float* __restrict__ accum, int B)
{
    const int b = blockIdx.x, lane = threadIdx.x;
    const float* U = uv + (size_t)b * 64;
    const float* V = uv + (size_t)(B + b) * 64;
    float prod = (lane < K_TAGS) ? U[lane] * V[lane] : 0.f;
    #pragma unroll
    for (int off = 32; off; off >>= 1) prod += __shfl_down(prod, off, 64);
    if (lane == 0) {
        float z = (U[K_TAGS] + V[K_TAGS] + LOG2F(prod)) * LN2;
        atomicAdd(&accum[0], z);
    }
}

__global__ void finalize_kernel(const float* __restrict__ accum,
                                float* __restrict__ out, float invB)
{
    out[0] = (accum[0] - accum[1]) * invB;
}

extern "C" void kernel_launch(void* const* d_in, const int* in_sizes, int n_in,
                              void* d_out, int out_size, void* d_ws, size_t ws_size,
                              hipStream_t stream)
{
    const float* scores  = (const float*)d_in[0];
    const int*   targets = (const int*)d_in[1];
    const int*   lengths = (const int*)d_in[2];
    const int B = in_sizes[2];

    float* accum = (float*)d_ws;
    float* uv    = (float*)d_ws + 16;     // u[B][64] then v[B][64]
    hipMemsetAsync(accum, 0, 2 * sizeof(float), stream);
    crf_fwd_kernel<<<2 * B, 256, 0, stream>>>(scores, targets, lengths, accum, uv);
    combine_kernel<<<B, 64, 0, stream>>>(uv, accum, B);
    finalize_kernel<<<1, 1, 0, stream>>>(accum, (float*)d_out, 1.0f / (float)B);
}